// Round 1
// 342.317 us; speedup vs baseline: 1.0160x; 1.0160x over previous
//
#include <hip/hip_runtime.h>
#include <cstdint>
#include <cstddef>

// Problem constants
#define BB 4
#define TT 4096
#define EE 1024
#define HH 16
#define SSLOTS 64
#define DD 64
#define MM (BB*TT)   // 16384

typedef unsigned short u16;
typedef __attribute__((ext_vector_type(8))) short s16x8;     // 8 bf16 (4 VGPRs) MFMA frag
typedef __attribute__((ext_vector_type(4))) float f32x4;     // MFMA acc
typedef __attribute__((ext_vector_type(8))) unsigned short us8v;
typedef __attribute__((ext_vector_type(4))) unsigned short us4v;

#define MFMA16(a, b, c) __builtin_amdgcn_mfma_f32_16x16x32_bf16((a), (b), (c), 0, 0, 0)

__device__ __forceinline__ u16 f2bf(float x) {
  union { float f; uint32_t u; } c; c.f = x;
  uint32_t u = c.u;
  u += 0x7fffu + ((u >> 16) & 1u);   // round-to-nearest-even
  return (u16)(u >> 16);
}

__device__ __forceinline__ float bf2f(u16 x) {
  union { uint32_t u; float f; } c; c.u = ((uint32_t)x) << 16;
  return c.f;
}

// async global->LDS, 16B per lane. LDS dest must be base + lane*16 (wave-contiguous).
__device__ __forceinline__ void async16(const void* g, void* l) {
  auto lp = reinterpret_cast<__attribute__((address_space(3))) void*>(
      reinterpret_cast<uintptr_t>(l));
  auto gp = reinterpret_cast<const __attribute__((address_space(1))) void*>(
      reinterpret_cast<uintptr_t>(g));
  __builtin_amdgcn_global_load_lds(gp, lp, 16, 0, 0);
}

// Apply RoPE to an 8-wide bf16 chunk at feature offset d0=p*8 of row t.
__device__ __forceinline__ us8v rope8(us8v kv, const float* __restrict__ rcp,
                                      const float* __restrict__ rsp) {
  float e[8];
#pragma unroll
  for (int m = 0; m < 8; ++m) e[m] = bf2f((u16)kv[m]);
  us8v o;
#pragma unroll
  for (int j = 0; j < 4; ++j) {
    float c0 = rcp[2 * j], c1 = rcp[2 * j + 1];
    float s0 = rsp[2 * j], s1 = rsp[2 * j + 1];
    o[2 * j]     = f2bf(e[2 * j] * c0 - e[2 * j + 1] * s0);
    o[2 * j + 1] = f2bf(e[2 * j + 1] * c1 + e[2 * j] * s1);
  }
  return o;
}

// ---------------- fused prep: cvt x, cvt 4 weights, rope tables — one launch ----------------
__global__ __launch_bounds__(256) void k_prep(const float* __restrict__ x,
                                              const float* __restrict__ w0,
                                              const float* __restrict__ w1,
                                              const float* __restrict__ w2,
                                              const float* __restrict__ w3,
                                              u16* __restrict__ x16,
                                              u16* __restrict__ dW,
                                              u16* __restrict__ dWo,
                                              float* __restrict__ rc,
                                              float* __restrict__ rs) {
  int bid = blockIdx.x;
  if (bid < 16384) {                    // x: 16.7M floats
    int i = (bid * 256 + threadIdx.x) * 4;
    float4 v = *(const float4*)(x + i);
    us4v o = { f2bf(v.x), f2bf(v.y), f2bf(v.z), f2bf(v.w) };
    *(us4v*)(x16 + i) = o;
  } else if (bid < 16384 + 4096) {      // 4 weight matrices, 1024 blocks each
    int bb = bid - 16384;
    int sel = bb >> 10;
    const float* s = (sel == 0) ? w0 : (sel == 1) ? w1 : (sel == 2) ? w2 : w3;
    u16* d = (sel < 3) ? (dW + (size_t)sel * EE * EE) : dWo;
    int i = ((bb & 1023) * 256 + threadIdx.x) * 4;
    float4 v = *(const float4*)(s + i);
    us4v o = { f2bf(v.x), f2bf(v.y), f2bf(v.z), f2bf(v.w) };
    *(us4v*)(d + i) = o;
  } else {                              // rope: 131072 entries, 512 blocks
    int i = (bid - 16384 - 4096) * 256 + threadIdx.x;
    int t = i >> 5, f = i & 31;
    double invf = pow(10000.0, -(double)(2 * f) / 64.0);
    double th = fmod((double)t * invf, 6.28318530717958647692528676655900577);
    rc[i] = (float)cos(th);
    rs[i] = (float)sin(th);
  }
}

// ==================== 256x256 8-phase GEMM (T1+T2+T3+T4+T5) ====================
// C(256x256) = A(256xK) * B(256xK)^T, K=1024, bf16 in, fp32 acc.
// 512 threads = 8 waves (2 wave-rows x 4 wave-cols); per-wave output 128x64 = acc[8][4].
// LDS 128 KiB = 2 bufs x 4 regions x 16 KB. Region = one K-half of A or B:
//   [256 rows][32 kcols] bf16 (64-B rows).  Region offsets within a buffer:
//   Ak0 @0, Ak1 @16384, Bk0 @32768, Bk1 @49152.  Buffers @0 / @65536.
// Bank swizzle (T2): byte ^= ((row>>1)&3)<<4 — applied on ds_read addr AND on the
// per-lane GLOBAL source column for global_load_lds (LDS dest stays linear).
// Schedule (T3+T4): per K-tile 4 phases {k0/imLo, k0/imHi, k1/imLo, k1/imHi};
// each phase stages one 16KB half: ph1->Ak1(t+1), ph2->Bk1(t+1),
// ph3->Ak0(t+2) (into CURRENT buf: its k0 regions are dead after ph2),
// ph4->Bk0(t+2); one counted s_waitcnt vmcnt(4) per tile at ph4 (never 0 in
// steady state: the 2 newest halves — t+2's k0 — stay in flight across the
// boundary; everything tile t+1 reads is landed before the barrier).

__device__ __forceinline__ void mm16(f32x4 (&acc)[8][4], const s16x8* a,
                                     const s16x8* b, int ab) {
#pragma unroll
  for (int im = 0; im < 4; ++im)
#pragma unroll
    for (int in = 0; in < 4; ++in)
      acc[ab + im][in] = MFMA16(a[im], b[in], acc[ab + im][in]);
}

__device__ __forceinline__ void gemm256(const u16* __restrict__ A,
                                        const u16* __restrict__ B,
                                        char* smem, f32x4 (&acc)[8][4]) {
  const int tid = threadIdx.x, lane = tid & 63, wave = tid >> 6;
  const int l16 = lane & 15, q4 = lane >> 4;
  const int wrow = (wave >> 2) * 128;
  const int wcol = (wave & 3) * 64;

  // staging constants: per wave 2 x global_load_lds(16B) per 16KB half.
  // LDS dest linear: wave*2048 + lane*16.  Global source col pre-swizzled.
  const int sr0 = wave * 32 + (lane >> 2);
  const int sr1 = sr0 + 16;
  const int sc  = (lane & 3) * 16;
  const size_t ga0 = (size_t)sr0 * 2048 + (size_t)(sc ^ (((sr0 >> 1) & 3) << 4));
  const size_t ga1 = (size_t)sr1 * 2048 + (size_t)(sc ^ (((sr1 >> 1) & 3) << 4));
  const int lo0 = sr0 * 64 + sc;
  const int lo1 = sr1 * 64 + sc;
  const char* Ab = (const char*)A;
  const char* Bb = (const char*)B;

  // fragment LDS byte offsets (within a region), swizzled
  int offA[8], offB[4];
#pragma unroll
  for (int f = 0; f < 8; ++f) {
    int r = wrow + f * 16 + l16;
    offA[f] = (r * 64 + q4 * 16) ^ (((r >> 1) & 3) << 4);
  }
#pragma unroll
  for (int f = 0; f < 4; ++f) {
    int r = wcol + f * 16 + l16;
    offB[f] = (r * 64 + q4 * 16) ^ (((r >> 1) & 3) << 4);
  }

#define STG(dst, srcb, kb) do { \
    async16((srcb) + (size_t)(kb) + ga0, (dst) + lo0); \
    async16((srcb) + (size_t)(kb) + ga1, (dst) + lo1); } while (0)

  // prologue: tile0 (all 4 halves) -> buf0; tile1 k0 halves -> buf1.
  // vmcnt(4): tile0 fully landed, tile1-k0 (4 loads) may fly.
  STG(smem +     0, Ab, 0);
  STG(smem + 32768, Bb, 0);
  STG(smem + 16384, Ab, 64);
  STG(smem + 49152, Bb, 64);
  STG(smem + 65536 +     0, Ab, 128);
  STG(smem + 65536 + 32768, Bb, 128);
  asm volatile("s_waitcnt vmcnt(4)" ::: "memory");
  __builtin_amdgcn_s_barrier();

  for (int tau = 0; tau < 16; ++tau) {
    char* cb = smem + ((tau & 1) << 16);
    char* nb = smem + (((tau + 1) & 1) << 16);
    const char* Ak0 = cb;
    const char* Ak1 = cb + 16384;
    const char* Bk0 = cb + 32768;
    const char* Bk1 = cb + 49152;
    const int kb1 = (tau + 1) << 7;   // next tile's k byte offset
    const int kb2 = (tau + 2) << 7;
    const bool st1 = tau < 15, st2 = tau < 14;

    s16x8 a[4], b[4];

    // ---- phase 1: k-half 0, A rows [wrow, wrow+64)
#pragma unroll
    for (int f = 0; f < 4; ++f) a[f] = *(const s16x8*)(Ak0 + offA[f]);
#pragma unroll
    for (int f = 0; f < 4; ++f) b[f] = *(const s16x8*)(Bk0 + offB[f]);
    if (st1) STG(nb + 16384, Ab, kb1 + 64);        // A k1 (t+1)
    __builtin_amdgcn_s_barrier();
    asm volatile("s_waitcnt lgkmcnt(0)" ::: "memory");
    __builtin_amdgcn_sched_barrier(0);
    __builtin_amdgcn_s_setprio(1);
    mm16(acc, a, b, 0);
    __builtin_amdgcn_s_setprio(0);
    __builtin_amdgcn_s_barrier();

    // ---- phase 2: k-half 0, A rows [wrow+64, wrow+128) (reuse b)
#pragma unroll
    for (int f = 0; f < 4; ++f) a[f] = *(const s16x8*)(Ak0 + offA[4 + f]);
    if (st1) STG(nb + 49152, Bb, kb1 + 64);        // B k1 (t+1)
    __builtin_amdgcn_s_barrier();
    asm volatile("s_waitcnt lgkmcnt(0)" ::: "memory");
    __builtin_amdgcn_sched_barrier(0);
    __builtin_amdgcn_s_setprio(1);
    mm16(acc, a, b, 4);
    __builtin_amdgcn_s_setprio(0);
    __builtin_amdgcn_s_barrier();

    // ---- phase 3: k-half 1, A rows [wrow, wrow+64), new b
#pragma unroll
    for (int f = 0; f < 4; ++f) a[f] = *(const s16x8*)(Ak1 + offA[f]);
#pragma unroll
    for (int f = 0; f < 4; ++f) b[f] = *(const s16x8*)(Bk1 + offB[f]);
    if (st2) STG(cb, Ab, kb2);                     // A k0 (t+2) -> current buf (k0 dead)
    __builtin_amdgcn_s_barrier();
    asm volatile("s_waitcnt lgkmcnt(0)" ::: "memory");
    __builtin_amdgcn_sched_barrier(0);
    __builtin_amdgcn_s_setprio(1);
    mm16(acc, a, b, 0);
    __builtin_amdgcn_s_setprio(0);
    __builtin_amdgcn_s_barrier();

    // ---- phase 4: k-half 1, A rows [wrow+64, wrow+128)
#pragma unroll
    for (int f = 0; f < 4; ++f) a[f] = *(const s16x8*)(Ak1 + offA[4 + f]);
    if (st2) STG(cb + 32768, Bb, kb2);             // B k0 (t+2)
    if (tau < 14) asm volatile("s_waitcnt vmcnt(4)" ::: "memory");
    else          asm volatile("s_waitcnt vmcnt(0)" ::: "memory");
    __builtin_amdgcn_s_barrier();
    asm volatile("s_waitcnt lgkmcnt(0)" ::: "memory");
    __builtin_amdgcn_sched_barrier(0);
    __builtin_amdgcn_s_setprio(1);
    mm16(acc, a, b, 4);
    __builtin_amdgcn_s_setprio(0);
    __builtin_amdgcn_s_barrier();
  }
#undef STG
}

// ---------------- fused QKV GEMM (rope applied later in stage2/3) ----------------
// grid: 768 blocks = 64 m-tiles x 12 n-tiles, m-fastest, XCD-chunked swizzle
__global__ __launch_bounds__(512, 2) void k_gemm_qkv(const u16* __restrict__ A,
                                                     const u16* __restrict__ Bw,
                                                     u16* __restrict__ q16,
                                                     u16* __restrict__ k16,
                                                     u16* __restrict__ v16) {
  __shared__ char smem[131072];
  const int bid = blockIdx.x;
  const int swz = (bid & 7) * 96 + (bid >> 3);   // 768 % 8 == 0, bijective
  const int mt = swz & 63, nt = swz >> 6;
  const int m0 = mt * 256, n0 = nt * 256;

  f32x4 acc[8][4];
#pragma unroll
  for (int i = 0; i < 8; ++i)
#pragma unroll
    for (int j = 0; j < 4; ++j) acc[i][j] = (f32x4){0.f, 0.f, 0.f, 0.f};

  gemm256(A + (size_t)m0 * 1024, Bw + (size_t)n0 * 1024, smem, acc);

  const int tid = threadIdx.x, lane = tid & 63, wave = tid >> 6;
  const int l16 = lane & 15, q4 = lane >> 4;
  const int wrow = (wave >> 2) * 128, wn = (wave & 3) * 64;
  const int which = n0 >> 10;        // 0=Q,1=K,2=V (uniform per block; 1024%256==0)
  const int nbl = n0 & 1023;
  u16* dst = (which == 0) ? q16 : ((which == 1) ? k16 : v16);

#pragma unroll
  for (int im = 0; im < 8; ++im)
#pragma unroll
    for (int in = 0; in < 4; ++in)
#pragma unroll
      for (int reg = 0; reg < 4; ++reg) {
        float v = acc[im][in][reg];
        int m = m0 + wrow + im * 16 + q4 * 4 + reg;
        int nn = nbl + wn + in * 16 + l16;
        int bq = m >> 12, t = m & 4095;
        int h = nn >> 6, d = nn & 63;
        dst[((size_t)(bq * HH + h) * TT + t) * 64 + d] = f2bf(v);
      }
}

// ---------------- plain out GEMM (fp32 epilogue) ----------------
// grid: 256 blocks = 64 m-tiles x 4 n-tiles, m-fastest, XCD swizzle
__global__ __launch_bounds__(512, 2) void k_gemm_out(const u16* __restrict__ A,
                                                     const u16* __restrict__ Bw,
                                                     float* __restrict__ C) {
  __shared__ char smem[131072];
  const int bid = blockIdx.x;
  const int swz = (bid & 7) * 32 + (bid >> 3);   // 256 % 8 == 0, bijective
  const int mt = swz & 63, nt = swz >> 6;
  const int m0 = mt * 256, n0 = nt * 256;

  f32x4 acc[8][4];
#pragma unroll
  for (int i = 0; i < 8; ++i)
#pragma unroll
    for (int j = 0; j < 4; ++j) acc[i][j] = (f32x4){0.f, 0.f, 0.f, 0.f};

  gemm256(A + (size_t)m0 * 1024, Bw + (size_t)n0 * 1024, smem, acc);

  const int tid = threadIdx.x, lane = tid & 63, wave = tid >> 6;
  const int l16 = lane & 15, q4 = lane >> 4;
  const int wrow = (wave >> 2) * 128, wn = (wave & 3) * 64;
#pragma unroll
  for (int im = 0; im < 8; ++im)
#pragma unroll
    for (int in = 0; in < 4; ++in)
#pragma unroll
      for (int reg = 0; reg < 4; ++reg) {
        int m = m0 + wrow + im * 16 + q4 * 4 + reg;
        int n = n0 + wn + in * 16 + l16;
        C[(size_t)m * 1024 + n] = acc[im][in][reg];
      }
}

// ---------------- stage 2: rope(K) -> write logits -> softmax -> slot_state ----------------
// grid: 512 blocks = 64 (b*h) x 8 t-blocks; each block loops 4 chunks of 128 t
__global__ __launch_bounds__(256) void k_stage2(const u16* __restrict__ K16g,
                                                const u16* __restrict__ V16g,
                                                const float* __restrict__ SKg,
                                                const float* __restrict__ rc,
                                                const float* __restrict__ rs,
                                                float* __restrict__ SSb) {
  const int tid = threadIdx.x, lane = tid & 63, wave = tid >> 6;
  const int l16 = lane & 15, q4 = lane >> 4, q8 = q4 * 8;
  const int bh = blockIdx.x >> 3, cb = blockIdx.x & 7;
  const int h = bh & 15;

  __shared__ u16 Ks[128 * 88];    // [t][d] stride 88
  __shared__ u16 Vs[64 * 136];    // [d][t] stride 136
  __shared__ u16 SKs[64 * 88];    // [s][d]
  u16* ww = Ks;                   // reuse as WW^T [s=64][t=128] stride 136

  const float* skh = SKg + (size_t)h * (SSLOTS * DD);
  for (int i = tid; i < 4096; i += 256)
    SKs[(i >> 6) * 88 + (i & 63)] = f2bf(skh[i]);

  f32x4 a2[4];
#pragma unroll
  for (int in = 0; in < 4; ++in) a2[in] = (f32x4){0.f, 0.f, 0.f, 0.f};

  const int w32 = wave * 32;
  for (int cc = 0; cc < 4; ++cc) {
    const int tg0 = cb * 512 + cc * 128;
    __syncthreads();   // SKs visible (cc=0) / prev-iter LDS reads done

    const u16* ks = K16g + ((size_t)bh * TT + tg0) * 64;
    for (int idx = tid; idx < 1024; idx += 256) {
      int t = idx >> 3, p = idx & 7;
      us8v kv = *(const us8v*)(ks + (size_t)t * 64 + p * 8);
      int fi = (tg0 + t) * 32 + ((p * 8) & 31);
      us8v kr = rope8(kv, rc + fi, rs + fi);
      *(us8v*)&Ks[t * 88 + p * 8] = kr;
    }
    const u16* vsrc = V16g + ((size_t)bh * TT + tg0) * 64;
    for (int idx = tid; idx < 1024; idx += 256) {
      int t = idx & 127, dg = idx >> 7;
      us8v vv = *(const us8v*)(vsrc + (size_t)t * 64 + dg * 8);
#pragma unroll
      for (int j = 0; j < 8; ++j) Vs[(dg * 8 + j) * 136 + t] = vv[j];
    }
    __syncthreads();

    // MFMA1: WL[t][s] = K . SK^T   (wave owns 32 t-rows)
    f32x4 a1[2][4];
#pragma unroll
    for (int im = 0; im < 2; ++im)
#pragma unroll
      for (int in = 0; in < 4; ++in) a1[im][in] = (f32x4){0.f, 0.f, 0.f, 0.f};
#pragma unroll
    for (int ksx = 0; ksx < 2; ++ksx) {
      s16x8 afr0 = *(const s16x8*)&Ks[(w32 + l16) * 88 + ksx * 32 + q8];
      s16x8 afr1 = *(const s16x8*)&Ks[(w32 + 16 + l16) * 88 + ksx * 32 + q8];
#pragma unroll
      for (int in = 0; in < 4; ++in) {
        s16x8 bfr = *(const s16x8*)&SKs[(in * 16 + l16) * 88 + ksx * 32 + q8];
        a1[0][in] = MFMA16(afr0, bfr, a1[0][in]);
        a1[1][in] = MFMA16(afr1, bfr, a1[1][in]);
      }
    }
    __syncthreads();   // all waves done reading Ks before ww overwrite

    // softmax over s (64) per t-row; write WW^T bf16 into ww[s][t]
#pragma unroll
    for (int im = 0; im < 2; ++im)
#pragma unroll
      for (int reg = 0; reg < 4; ++reg) {
        float v0 = a1[im][0][reg] * 0.125f, v1 = a1[im][1][reg] * 0.125f;
        float v2 = a1[im][2][reg] * 0.125f, v3 = a1[im][3][reg] * 0.125f;
        float mx = fmaxf(fmaxf(v0, v1), fmaxf(v2, v3));
#pragma unroll
        for (int m = 1; m < 16; m <<= 1) mx = fmaxf(mx, __shfl_xor(mx, m));
        float e0 = __expf(v0 - mx), e1 = __expf(v1 - mx);
        float e2 = __expf(v2 - mx), e3 = __expf(v3 - mx);
        float sm = e0 + e1 + e2 + e3;
#pragma unroll
        for (int m = 1; m < 16; m <<= 1) sm += __shfl_xor(sm, m);
        float inv = 1.0f / sm;
        int tl = w32 + im * 16 + q4 * 4 + reg;
        ww[(l16) * 136 + tl]      = f2bf(e0 * inv);
        ww[(16 + l16) * 136 + tl] = f2bf(e1 * inv);
        ww[(32 + l16) * 136 + tl] = f2bf(e2 * inv);
        ww[(48 + l16) * 136 + tl] = f2bf(e3 * inv);
      }
    __syncthreads();

    // MFMA2: SS[s][d] += WW^T . V   (wave owns 16 s-rows, k = 128 t)
#pragma unroll
    for (int ksx = 0; ksx < 4; ++ksx) {
      s16x8 afr = *(const s16x8*)&ww[(wave * 16 + l16) * 136 + ksx * 32 + q8];
#pragma unroll
      for (int in = 0; in < 4; ++in) {
        s16x8 bfr = *(const s16x8*)&Vs[(in * 16 + l16) * 136 + ksx * 32 + q8];
        a2[in] = MFMA16(afr, bfr, a2[in]);
      }
    }
  }

  const float invT = 1.0f / (float)TT;
#pragma unroll
  for (int in = 0; in < 4; ++in)
#pragma unroll
    for (int reg = 0; reg < 4; ++reg) {
      int s = wave * 16 + q4 * 4 + reg;
      int d = in * 16 + l16;
      atomicAdd(&SSb[(size_t)bh * 4096 + s * 64 + d], a2[in][reg] * invT);
    }
}

// ---------------- stage 3: rope(Q) -> read logits -> softmax -> read_out ----------------
// grid: 2048 blocks = 64 (b*h) x 32 chunks of 128 t; 44 KB LDS
__global__ __launch_bounds__(256) void k_stage3(const u16* __restrict__ Q16g,
                                                const float* __restrict__ SSg,
                                                const float* __restrict__ rc,
                                                const float* __restrict__ rs,
                                                u16* __restrict__ RO) {
  const int tid = threadIdx.x, lane = tid & 63, wave = tid >> 6;
  const int l16 = lane & 15, q4 = lane >> 4, q8 = q4 * 8;
  const int bh = blockIdx.x >> 5, ck = blockIdx.x & 31;
  const int b = bh >> 4, h = bh & 15;
  const int tg0 = ck * 128;

  __shared__ u16 Qs[128 * 88];      // [t][d]; reused as RW [t][s]
  __shared__ u16 ss_sd[64 * 88];    // SS[s][d]
  __shared__ u16 ss_ds[64 * 88];    // SS^T[d][s]
  u16* RWs = Qs;

  const float* ssp = SSg + (size_t)bh * 4096;
  for (int i = tid; i < 4096; i += 256) {
    u16 u = f2bf(ssp[i]);
    int s = i >> 6, d = i & 63;
    ss_sd[s * 88 + d] = u;
    ss_ds[d * 88 + s] = u;
  }
  const u16* qsrc = Q16g + ((size_t)bh * TT + tg0) * 64;
  for (int idx = tid; idx < 1024; idx += 256) {
    int t = idx >> 3, p = idx & 7;
    us8v qv = *(const us8v*)(qsrc + (size_t)t * 64 + p * 8);
    int fi = (tg0 + t) * 32 + ((p * 8) & 31);
    us8v qr = rope8(qv, rc + fi, rs + fi);
    *(us8v*)&Qs[t * 88 + p * 8] = qr;
  }
  __syncthreads();

  const int w32 = wave * 32;
  // MFMA3: RL[t][s] = Q . SS^T  (wave owns 32 t-rows)
  f32x4 a3[2][4];
#pragma unroll
  for (int i = 0; i < 2; ++i)
#pragma unroll
    for (int j = 0; j < 4; ++j) a3[i][j] = (f32x4){0.f, 0.f, 0.f, 0.f};
#pragma unroll
  for (int ksx = 0; ksx < 2; ++ksx) {
    s16x8 afr[2];
#pragma unroll
    for (int im = 0; im < 2; ++im)
      afr[im] = *(const s16x8*)&Qs[(w32 + im * 16 + l16) * 88 + ksx * 32 + q8];
#pragma unroll
    for (int in = 0; in < 4; ++in) {
      s16x8 bfr = *(const s16x8*)&ss_sd[(in * 16 + l16) * 88 + ksx * 32 + q8];
#pragma unroll
      for (int im = 0; im < 2; ++im) a3[im][in] = MFMA16(afr[im], bfr, a3[im][in]);
    }
  }
  __syncthreads();

  // softmax over s, write RW[t][s] bf16
#pragma unroll
  for (int im = 0; im < 2; ++im)
#pragma unroll
    for (int reg = 0; reg < 4; ++reg) {
      float v0 = a3[im][0][reg] * 0.125f, v1 = a3[im][1][reg] * 0.125f;
      float v2 = a3[im][2][reg] * 0.125f, v3 = a3[im][3][reg] * 0.125f;
      float mx = fmaxf(fmaxf(v0, v1), fmaxf(v2, v3));
#pragma unroll
      for (int m = 1; m < 16; m <<= 1) mx = fmaxf(mx, __shfl_xor(mx, m));
      float e0 = __expf(v0 - mx), e1 = __expf(v1 - mx);
      float e2 = __expf(v2 - mx), e3 = __expf(v3 - mx);
      float sm = e0 + e1 + e2 + e3;
#pragma unroll
      for (int m = 1; m < 16; m <<= 1) sm += __shfl_xor(sm, m);
      float inv = 1.0f / sm;
      int tl = w32 + im * 16 + q4 * 4 + reg;
      RWs[tl * 88 + l16]      = f2bf(e0 * inv);
      RWs[tl * 88 + 16 + l16] = f2bf(e1 * inv);
      RWs[tl * 88 + 32 + l16] = f2bf(e2 * inv);
      RWs[tl * 88 + 48 + l16] = f2bf(e3 * inv);
    }
  __syncthreads();

  // MFMA4: RO[t][d] = RW . SS
  f32x4 a4[2][4];
#pragma unroll
  for (int i = 0; i < 2; ++i)
#pragma unroll
    for (int j = 0; j < 4; ++j) a4[i][j] = (f32x4){0.f, 0.f, 0.f, 0.f};
#pragma unroll
  for (int ksx = 0; ksx < 2; ++ksx) {
    s16x8 afr[2];
#pragma unroll
    for (int im = 0; im < 2; ++im)
      afr[im] = *(const s16x8*)&RWs[(w32 + im * 16 + l16) * 88 + ksx * 32 + q8];
#pragma unroll
    for (int in = 0; in < 4; ++in) {
      s16x8 bfr = *(const s16x8*)&ss_ds[(in * 16 + l16) * 88 + ksx * 32 + q8];
#pragma unroll
      for (int im = 0; im < 2; ++im) a4[im][in] = MFMA16(afr[im], bfr, a4[im][in]);
    }
  }

  // epilogue: RO bf16 [m][e] with m=b*T+t, e=h*64+d
#pragma unroll
  for (int im = 0; im < 2; ++im)
#pragma unroll
    for (int in = 0; in < 4; ++in)
#pragma unroll
      for (int reg = 0; reg < 4; ++reg) {
        int t = tg0 + w32 + im * 16 + q4 * 4 + reg;
        int d = in * 16 + l16;
        RO[((size_t)b * TT + t) * 1024 + h * 64 + d] = f2bf(a4[im][in][reg]);
      }
}

// ---------------- launch ----------------
extern "C" void kernel_launch(void* const* d_in, const int* in_sizes, int n_in,
                              void* d_out, int out_size, void* d_ws, size_t ws_size,
                              hipStream_t stream) {
  const float* x  = (const float*)d_in[0];
  const float* Wq = (const float*)d_in[1];
  const float* Wk = (const float*)d_in[2];
  const float* Wv = (const float*)d_in[3];
  const float* Wo = (const float*)d_in[4];
  const float* SK = (const float*)d_in[5];
  float* out = (float*)d_out;

  // workspace carve (needs ~145 MB)
  char* w = (char*)d_ws;
  u16* x16 = (u16*)w;   w += (size_t)MM * EE * 2;          // 33.5 MB
  u16* W16 = (u16*)w;   w += (size_t)3 * EE * EE * 2;      // 6.3 MB
  u16* Wo16 = (u16*)w;  w += (size_t)EE * EE * 2;          // 2.1 MB
  u16* Q16 = (u16*)w;   w += (size_t)BB * HH * TT * DD * 2; // 33.5 MB
  u16* K16 = (u16*)w;   w += (size_t)BB * HH * TT * DD * 2;
  u16* V16 = (u16*)w;   w += (size_t)BB * HH * TT * DD * 2;
  float* SSb = (float*)w; w += (size_t)BB * HH * SSLOTS * DD * 4; // 1 MB
  float* rc = (float*)w;  w += (size_t)TT * 32 * 4;
  float* rs = (float*)w;  w += (size_t)TT * 32 * 4;
  u16* RO16 = x16;  // x16 dead after QKV GEMM

  if ((size_t)(w - (char*)d_ws) > ws_size) return;  // ws too small -> loud failure

  k_prep<<<16384 + 4096 + 512, 256, 0, stream>>>(x, Wq, Wk, Wv, Wo, x16, W16, Wo16, rc, rs);

  k_gemm_qkv<<<768, 512, 0, stream>>>(x16, W16, Q16, K16, V16);

  hipMemsetAsync(SSb, 0, (size_t)BB * HH * SSLOTS * DD * 4, stream);
  k_stage2<<<512, 256, 0, stream>>>(K16, V16, SK, rc, rs, SSb);
  k_stage3<<<2048, 256, 0, stream>>>(Q16, SSb, rc, rs, RO16);

  k_gemm_out<<<256, 512, 0, stream>>>(RO16, Wo16, out);
}

// Round 3
// 333.098 us; speedup vs baseline: 1.0441x; 1.0277x over previous
//
#include <hip/hip_runtime.h>
#include <cstdint>
#include <cstddef>

// Problem constants
#define BB 4
#define TT 4096
#define EE 1024
#define HH 16
#define SSLOTS 64
#define DD 64
#define MM (BB*TT)   // 16384

typedef unsigned short u16;
typedef __attribute__((ext_vector_type(8))) short s16x8;     // 8 bf16 (4 VGPRs) MFMA frag
typedef __attribute__((ext_vector_type(4))) float f32x4;     // MFMA acc
typedef __attribute__((ext_vector_type(8))) unsigned short us8v;
typedef __attribute__((ext_vector_type(4))) unsigned short us4v;

#define MFMA16(a, b, c) __builtin_amdgcn_mfma_f32_16x16x32_bf16((a), (b), (c), 0, 0, 0)

__device__ __forceinline__ u16 f2bf(float x) {
  union { float f; uint32_t u; } c; c.f = x;
  uint32_t u = c.u;
  u += 0x7fffu + ((u >> 16) & 1u);   // round-to-nearest-even
  return (u16)(u >> 16);
}

__device__ __forceinline__ float bf2f(u16 x) {
  union { uint32_t u; float f; } c; c.u = ((uint32_t)x) << 16;
  return c.f;
}

// async global->LDS, 16B per lane. LDS dest must be base + lane*16 (wave-contiguous).
__device__ __forceinline__ void async16(const void* g, void* l) {
  auto lp = reinterpret_cast<__attribute__((address_space(3))) void*>(
      reinterpret_cast<uintptr_t>(l));
  auto gp = reinterpret_cast<const __attribute__((address_space(1))) void*>(
      reinterpret_cast<uintptr_t>(g));
  __builtin_amdgcn_global_load_lds(gp, lp, 16, 0, 0);
}

// Apply RoPE to an 8-wide bf16 chunk at feature offset d0=p*8 of row t.
__device__ __forceinline__ us8v rope8(us8v kv, const float* __restrict__ rcp,
                                      const float* __restrict__ rsp) {
  float e[8];
#pragma unroll
  for (int m = 0; m < 8; ++m) e[m] = bf2f((u16)kv[m]);
  us8v o;
#pragma unroll
  for (int j = 0; j < 4; ++j) {
    float c0 = rcp[2 * j], c1 = rcp[2 * j + 1];
    float s0 = rsp[2 * j], s1 = rsp[2 * j + 1];
    o[2 * j]     = f2bf(e[2 * j] * c0 - e[2 * j + 1] * s0);
    o[2 * j + 1] = f2bf(e[2 * j + 1] * c1 + e[2 * j] * s1);
  }
  return o;
}

// ---------------- fused prep: cvt x, cvt 4 weights, rope tables — one launch ----------------
__global__ __launch_bounds__(256) void k_prep(const float* __restrict__ x,
                                              const float* __restrict__ w0,
                                              const float* __restrict__ w1,
                                              const float* __restrict__ w2,
                                              const float* __restrict__ w3,
                                              u16* __restrict__ x16,
                                              u16* __restrict__ dW,
                                              u16* __restrict__ dWo,
                                              float* __restrict__ rc,
                                              float* __restrict__ rs) {
  int bid = blockIdx.x;
  if (bid < 16384) {                    // x: 16.7M floats
    int i = (bid * 256 + threadIdx.x) * 4;
    float4 v = *(const float4*)(x + i);
    us4v o = { f2bf(v.x), f2bf(v.y), f2bf(v.z), f2bf(v.w) };
    *(us4v*)(x16 + i) = o;
  } else if (bid < 16384 + 4096) {      // 4 weight matrices, 1024 blocks each
    int bb = bid - 16384;
    int sel = bb >> 10;
    const float* s = (sel == 0) ? w0 : (sel == 1) ? w1 : (sel == 2) ? w2 : w3;
    u16* d = (sel < 3) ? (dW + (size_t)sel * EE * EE) : dWo;
    int i = ((bb & 1023) * 256 + threadIdx.x) * 4;
    float4 v = *(const float4*)(s + i);
    us4v o = { f2bf(v.x), f2bf(v.y), f2bf(v.z), f2bf(v.w) };
    *(us4v*)(d + i) = o;
  } else {                              // rope: 131072 entries, 512 blocks
    int i = (bid - 16384 - 4096) * 256 + threadIdx.x;
    int t = i >> 5, f = i & 31;
    double invf = pow(10000.0, -(double)(2 * f) / 64.0);
    double th = fmod((double)t * invf, 6.28318530717958647692528676655900577);
    rc[i] = (float)cos(th);
    rs[i] = (float)sin(th);
  }
}

// ==================== 256x256 8-phase GEMM (T1+T2+T3+T4+T5) ====================
// C(256x256) = A(256xK) * B(256xK)^T, K=1024, bf16 in, fp32 acc.
// 512 threads = 8 waves (2 wave-rows x 4 wave-cols); per-wave output 128x64 = acc[8][4].
// LDS 128 KiB = 2 bufs x 4 regions x 16 KB. Region = one K-half of A or B:
//   [256 rows][32 kcols] bf16 (64-B rows).  Region offsets within a buffer:
//   Ak0 @0, Ak1 @16384, Bk0 @32768, Bk1 @49152.  Buffers @0 / @65536.
// Bank swizzle (T2): byte ^= ((row>>1)&3)<<4 — applied on ds_read addr AND on the
// per-lane GLOBAL source column for global_load_lds (LDS dest stays linear).
// Schedule (T3+T4): per K-tile 4 phases {k0/imLo, k0/imHi, k1/imLo, k1/imHi};
// each phase stages one 16KB half: ph1->Ak1(t+1), ph2->Bk1(t+1),
// ph3->Ak0(t+2) (into CURRENT buf: its k0 regions are dead after ph2),
// ph4->Bk0(t+2).
// Counted waits (vmcnt(6)) at ph2 and ph4 — never 0 in steady state.
// Steady-state induction (per-wave outstanding queue, 2 loads/STG):
//   S4(t-1)=[t-1p2,t-1p3,t-1p4]=6; ph1 +tp1 -> 8; W(t,2): +tp2 ->10, vmcnt(6)
//   lands {t-1p2 (=Bk1(t), read t.ph3), t-1p3 (=Ak0(t+1))}; ph3 +2 ->8, ph4 +2
//   ->10, vmcnt(6) lands {t-1p4 (=Bk0(t+1)), tp1 (=Ak1(t+1))}; S4(t)=[p2,p3,p4].
//   Every region lands at a wait that precedes the barrier releasing its readers;
//   wait-before-barrier makes cross-wave LDS writes visible.
// Overwrite safety: ph3/ph4 write cb's k0 regions, whose last readers (ph1/ph2)
//   all passed lgkmcnt(0) + a trailing barrier before any wave reaches ph3.
// NOTE: no sched_barrier(0) here — ds_reads are compiler-visible loads, the
// compiler's dependency waitcnts protect them; a hard fence is the m141
// order-pinning anti-pattern that defeats compiler scheduling.

__device__ __forceinline__ void mm16(f32x4 (&acc)[8][4], const s16x8* a,
                                     const s16x8* b, int ab) {
#pragma unroll
  for (int im = 0; im < 4; ++im)
#pragma unroll
    for (int in = 0; in < 4; ++in)
      acc[ab + im][in] = MFMA16(a[im], b[in], acc[ab + im][in]);
}

__device__ __forceinline__ void gemm256(const u16* __restrict__ A,
                                        const u16* __restrict__ B,
                                        char* smem, f32x4 (&acc)[8][4]) {
  const int tid = threadIdx.x, lane = tid & 63, wave = tid >> 6;
  const int l16 = lane & 15, q4 = lane >> 4;
  const int wrow = (wave >> 2) * 128;
  const int wcol = (wave & 3) * 64;

  // staging constants: per wave 2 x global_load_lds(16B) per 16KB half.
  // LDS dest linear: wave*2048 + lane*16.  Global source col pre-swizzled.
  const int sr0 = wave * 32 + (lane >> 2);
  const int sr1 = sr0 + 16;
  const int sc  = (lane & 3) * 16;
  const size_t ga0 = (size_t)sr0 * 2048 + (size_t)(sc ^ (((sr0 >> 1) & 3) << 4));
  const size_t ga1 = (size_t)sr1 * 2048 + (size_t)(sc ^ (((sr1 >> 1) & 3) << 4));
  const int lo0 = sr0 * 64 + sc;
  const int lo1 = sr1 * 64 + sc;
  const char* Ab = (const char*)A;
  const char* Bb = (const char*)B;

  // fragment LDS byte offsets (within a region), swizzled
  int offA[8], offB[4];
#pragma unroll
  for (int f = 0; f < 8; ++f) {
    int r = wrow + f * 16 + l16;
    offA[f] = (r * 64 + q4 * 16) ^ (((r >> 1) & 3) << 4);
  }
#pragma unroll
  for (int f = 0; f < 4; ++f) {
    int r = wcol + f * 16 + l16;
    offB[f] = (r * 64 + q4 * 16) ^ (((r >> 1) & 3) << 4);
  }

#define STG(dst, srcb, kb) do { \
    async16((srcb) + (size_t)(kb) + ga0, (dst) + lo0); \
    async16((srcb) + (size_t)(kb) + ga1, (dst) + lo1); } while (0)

  // prologue: tile0 (all 4 halves) -> buf0; tile1 k0 halves -> buf1.
  // vmcnt(4): tile0 fully landed (8 oldest of 12 per wave), tile1-k0 may fly.
  STG(smem +     0, Ab, 0);
  STG(smem + 32768, Bb, 0);
  STG(smem + 16384, Ab, 64);
  STG(smem + 49152, Bb, 64);
  STG(smem + 65536 +     0, Ab, 128);
  STG(smem + 65536 + 32768, Bb, 128);
  asm volatile("s_waitcnt vmcnt(4)" ::: "memory");
  __builtin_amdgcn_s_barrier();

  for (int tau = 0; tau < 16; ++tau) {
    char* cb = smem + ((tau & 1) << 16);
    char* nb = smem + (((tau + 1) & 1) << 16);
    const char* Ak0 = cb;
    const char* Ak1 = cb + 16384;
    const char* Bk0 = cb + 32768;
    const char* Bk1 = cb + 49152;
    const int kb1 = (tau + 1) << 7;   // next tile's k byte offset
    const int kb2 = (tau + 2) << 7;
    const bool st1 = tau < 15, st2 = tau < 14;

    s16x8 a[4], b[4];

    // ---- phase 1: k-half 0, A rows [wrow, wrow+64)
#pragma unroll
    for (int f = 0; f < 4; ++f) a[f] = *(const s16x8*)(Ak0 + offA[f]);
#pragma unroll
    for (int f = 0; f < 4; ++f) b[f] = *(const s16x8*)(Bk0 + offB[f]);
    if (st1) STG(nb + 16384, Ab, kb1 + 64);        // A k1 (t+1)
    __builtin_amdgcn_s_barrier();
    asm volatile("s_waitcnt lgkmcnt(0)" ::: "memory");
    __builtin_amdgcn_s_setprio(1);
    mm16(acc, a, b, 0);
    __builtin_amdgcn_s_setprio(0);
    __builtin_amdgcn_s_barrier();

    // ---- phase 2: k-half 0, A rows [wrow+64, wrow+128) (reuse b)
#pragma unroll
    for (int f = 0; f < 4; ++f) a[f] = *(const s16x8*)(Ak0 + offA[4 + f]);
    if (st1) STG(nb + 49152, Bb, kb1 + 64);        // B k1 (t+1)
    if (st2) asm volatile("s_waitcnt vmcnt(6)" ::: "memory");
    else     asm volatile("s_waitcnt vmcnt(0)" ::: "memory");
    __builtin_amdgcn_s_barrier();
    asm volatile("s_waitcnt lgkmcnt(0)" ::: "memory");
    __builtin_amdgcn_s_setprio(1);
    mm16(acc, a, b, 4);
    __builtin_amdgcn_s_setprio(0);
    __builtin_amdgcn_s_barrier();

    // ---- phase 3: k-half 1, A rows [wrow, wrow+64), new b
#pragma unroll
    for (int f = 0; f < 4; ++f) a[f] = *(const s16x8*)(Ak1 + offA[f]);
#pragma unroll
    for (int f = 0; f < 4; ++f) b[f] = *(const s16x8*)(Bk1 + offB[f]);
    if (st2) STG(cb, Ab, kb2);                     // A k0 (t+2) -> current buf (k0 dead)
    __builtin_amdgcn_s_barrier();
    asm volatile("s_waitcnt lgkmcnt(0)" ::: "memory");
    __builtin_amdgcn_s_setprio(1);
    mm16(acc, a, b, 0);
    __builtin_amdgcn_s_setprio(0);
    __builtin_amdgcn_s_barrier();

    // ---- phase 4: k-half 1, A rows [wrow+64, wrow+128)
#pragma unroll
    for (int f = 0; f < 4; ++f) a[f] = *(const s16x8*)(Ak1 + offA[4 + f]);
    if (st2) STG(cb + 32768, Bb, kb2);             // B k0 (t+2)
    if (st2) asm volatile("s_waitcnt vmcnt(6)" ::: "memory");
    else     asm volatile("s_waitcnt vmcnt(0)" ::: "memory");
    __builtin_amdgcn_s_barrier();
    asm volatile("s_waitcnt lgkmcnt(0)" ::: "memory");
    __builtin_amdgcn_s_setprio(1);
    mm16(acc, a, b, 4);
    __builtin_amdgcn_s_setprio(0);
    __builtin_amdgcn_s_barrier();
  }
#undef STG
}

// ---------------- fused QKV GEMM (rope applied later in stage2/3) ----------------
// grid: 768 blocks = 64 m-tiles x 12 n-tiles.
// XCD swizzle: each XCD owns an 8-m-tile chunk (4 MB of A == one XCD's L2),
// n varies within the chunk -> A fetched from HBM ~once total.
__global__ __launch_bounds__(512, 2) void k_gemm_qkv(const u16* __restrict__ A,
                                                     const u16* __restrict__ Bw,
                                                     u16* __restrict__ q16,
                                                     u16* __restrict__ k16,
                                                     u16* __restrict__ v16) {
  __shared__ char smem[131072];
  const int bid = blockIdx.x;
  const int xcd = bid & 7, local = bid >> 3;       // local 0..95
  const int mt = xcd * 8 + (local & 7);
  const int nt = local >> 3;                        // 0..11
  const int m0 = mt * 256, n0 = nt * 256;

  f32x4 acc[8][4];
#pragma unroll
  for (int i = 0; i < 8; ++i)
#pragma unroll
    for (int j = 0; j < 4; ++j) acc[i][j] = (f32x4){0.f, 0.f, 0.f, 0.f};

  gemm256(A + (size_t)m0 * 1024, Bw + (size_t)n0 * 1024, smem, acc);

  const int tid = threadIdx.x, lane = tid & 63, wave = tid >> 6;
  const int l16 = lane & 15, q4 = lane >> 4;
  const int wrow = (wave >> 2) * 128, wn = (wave & 3) * 64;
  const int which = n0 >> 10;        // 0=Q,1=K,2=V (uniform per block; 1024%256==0)
  const int nbl = n0 & 1023;
  u16* dst = (which == 0) ? q16 : ((which == 1) ? k16 : v16);

#pragma unroll
  for (int im = 0; im < 8; ++im)
#pragma unroll
    for (int in = 0; in < 4; ++in)
#pragma unroll
      for (int reg = 0; reg < 4; ++reg) {
        float v = acc[im][in][reg];
        int m = m0 + wrow + im * 16 + q4 * 4 + reg;
        int nn = nbl + wn + in * 16 + l16;
        int bq = m >> 12, t = m & 4095;
        int h = nn >> 6, d = nn & 63;
        dst[((size_t)(bq * HH + h) * TT + t) * 64 + d] = f2bf(v);
      }
}

// ---------------- plain out GEMM (fp32 epilogue) ----------------
// grid: 256 blocks = 64 m-tiles x 4 n-tiles; XCD owns 8-m-tile chunk.
__global__ __launch_bounds__(512, 2) void k_gemm_out(const u16* __restrict__ A,
                                                     const u16* __restrict__ Bw,
                                                     float* __restrict__ C) {
  __shared__ char smem[131072];
  const int bid = blockIdx.x;
  const int xcd = bid & 7, local = bid >> 3;       // local 0..31
  const int mt = xcd * 8 + (local & 7);
  const int nt = local >> 3;                        // 0..3
  const int m0 = mt * 256, n0 = nt * 256;

  f32x4 acc[8][4];
#pragma unroll
  for (int i = 0; i < 8; ++i)
#pragma unroll
    for (int j = 0; j < 4; ++j) acc[i][j] = (f32x4){0.f, 0.f, 0.f, 0.f};

  gemm256(A + (size_t)m0 * 1024, Bw + (size_t)n0 * 1024, smem, acc);

  const int tid = threadIdx.x, lane = tid & 63, wave = tid >> 6;
  const int l16 = lane & 15, q4 = lane >> 4;
  const int wrow = (wave >> 2) * 128, wn = (wave & 3) * 64;
#pragma unroll
  for (int im = 0; im < 8; ++im)
#pragma unroll
    for (int in = 0; in < 4; ++in)
#pragma unroll
      for (int reg = 0; reg < 4; ++reg) {
        int m = m0 + wrow + im * 16 + q4 * 4 + reg;
        int n = n0 + wn + in * 16 + l16;
        C[(size_t)m * 1024 + n] = acc[im][in][reg];
      }
}

// ---------------- stage 2: rope(K) -> write logits -> softmax -> slot_state ----------------
// grid: 512 blocks = 64 (b*h) x 8 t-blocks; each block loops 4 chunks of 128 t
__global__ __launch_bounds__(256) void k_stage2(const u16* __restrict__ K16g,
                                                const u16* __restrict__ V16g,
                                                const float* __restrict__ SKg,
                                                const float* __restrict__ rc,
                                                const float* __restrict__ rs,
                                                float* __restrict__ SSb) {
  const int tid = threadIdx.x, lane = tid & 63, wave = tid >> 6;
  const int l16 = lane & 15, q4 = lane >> 4, q8 = q4 * 8;
  const int bh = blockIdx.x >> 3, cb = blockIdx.x & 7;
  const int h = bh & 15;

  __shared__ u16 Ks[128 * 88];    // [t][d] stride 88
  __shared__ u16 Vs[64 * 136];    // [d][t] stride 136
  __shared__ u16 SKs[64 * 88];    // [s][d]
  u16* ww = Ks;                   // reuse as WW^T [s=64][t=128] stride 136

  const float* skh = SKg + (size_t)h * (SSLOTS * DD);
  for (int i = tid; i < 4096; i += 256)
    SKs[(i >> 6) * 88 + (i & 63)] = f2bf(skh[i]);

  f32x4 a2[4];
#pragma unroll
  for (int in = 0; in < 4; ++in) a2[in] = (f32x4){0.f, 0.f, 0.f, 0.f};

  const int w32 = wave * 32;
  for (int cc = 0; cc < 4; ++cc) {
    const int tg0 = cb * 512 + cc * 128;
    __syncthreads();   // SKs visible (cc=0) / prev-iter LDS reads done

    const u16* ks = K16g + ((size_t)bh * TT + tg0) * 64;
    for (int idx = tid; idx < 1024; idx += 256) {
      int t = idx >> 3, p = idx & 7;
      us8v kv = *(const us8v*)(ks + (size_t)t * 64 + p * 8);
      int fi = (tg0 + t) * 32 + ((p * 8) & 31);
      us8v kr = rope8(kv, rc + fi, rs + fi);
      *(us8v*)&Ks[t * 88 + p * 8] = kr;
    }
    const u16* vsrc = V16g + ((size_t)bh * TT + tg0) * 64;
    for (int idx = tid; idx < 1024; idx += 256) {
      int t = idx & 127, dg = idx >> 7;
      us8v vv = *(const us8v*)(vsrc + (size_t)t * 64 + dg * 8);
#pragma unroll
      for (int j = 0; j < 8; ++j) Vs[(dg * 8 + j) * 136 + t] = vv[j];
    }
    __syncthreads();

    // MFMA1: WL[t][s] = K . SK^T   (wave owns 32 t-rows)
    f32x4 a1[2][4];
#pragma unroll
    for (int im = 0; im < 2; ++im)
#pragma unroll
      for (int in = 0; in < 4; ++in) a1[im][in] = (f32x4){0.f, 0.f, 0.f, 0.f};
#pragma unroll
    for (int ksx = 0; ksx < 2; ++ksx) {
      s16x8 afr0 = *(const s16x8*)&Ks[(w32 + l16) * 88 + ksx * 32 + q8];
      s16x8 afr1 = *(const s16x8*)&Ks[(w32 + 16 + l16) * 88 + ksx * 32 + q8];
#pragma unroll
      for (int in = 0; in < 4; ++in) {
        s16x8 bfr = *(const s16x8*)&SKs[(in * 16 + l16) * 88 + ksx * 32 + q8];
        a1[0][in] = MFMA16(afr0, bfr, a1[0][in]);
        a1[1][in] = MFMA16(afr1, bfr, a1[1][in]);
      }
    }
    __syncthreads();   // all waves done reading Ks before ww overwrite

    // softmax over s (64) per t-row; write WW^T bf16 into ww[s][t]
#pragma unroll
    for (int im = 0; im < 2; ++im)
#pragma unroll
      for (int reg = 0; reg < 4; ++reg) {
        float v0 = a1[im][0][reg] * 0.125f, v1 = a1[im][1][reg] * 0.125f;
        float v2 = a1[im][2][reg] * 0.125f, v3 = a1[im][3][reg] * 0.125f;
        float mx = fmaxf(fmaxf(v0, v1), fmaxf(v2, v3));
#pragma unroll
        for (int m = 1; m < 16; m <<= 1) mx = fmaxf(mx, __shfl_xor(mx, m));
        float e0 = __expf(v0 - mx), e1 = __expf(v1 - mx);
        float e2 = __expf(v2 - mx), e3 = __expf(v3 - mx);
        float sm = e0 + e1 + e2 + e3;
#pragma unroll
        for (int m = 1; m < 16; m <<= 1) sm += __shfl_xor(sm, m);
        float inv = 1.0f / sm;
        int tl = w32 + im * 16 + q4 * 4 + reg;
        ww[(l16) * 136 + tl]      = f2bf(e0 * inv);
        ww[(16 + l16) * 136 + tl] = f2bf(e1 * inv);
        ww[(32 + l16) * 136 + tl] = f2bf(e2 * inv);
        ww[(48 + l16) * 136 + tl] = f2bf(e3 * inv);
      }
    __syncthreads();

    // MFMA2: SS[s][d] += WW^T . V   (wave owns 16 s-rows, k = 128 t)
#pragma unroll
    for (int ksx = 0; ksx < 4; ++ksx) {
      s16x8 afr = *(const s16x8*)&ww[(wave * 16 + l16) * 136 + ksx * 32 + q8];
#pragma unroll
      for (int in = 0; in < 4; ++in) {
        s16x8 bfr = *(const s16x8*)&Vs[(in * 16 + l16) * 136 + ksx * 32 + q8];
        a2[in] = MFMA16(afr, bfr, a2[in]);
      }
    }
  }

  const float invT = 1.0f / (float)TT;
#pragma unroll
  for (int in = 0; in < 4; ++in)
#pragma unroll
    for (int reg = 0; reg < 4; ++reg) {
      int s = wave * 16 + q4 * 4 + reg;
      int d = in * 16 + l16;
      atomicAdd(&SSb[(size_t)bh * 4096 + s * 64 + d], a2[in][reg] * invT);
    }
}

// ---------------- stage 3: rope(Q) -> read logits -> softmax -> read_out ----------------
// grid: 2048 blocks = 64 (b*h) x 32 chunks of 128 t; 44 KB LDS
__global__ __launch_bounds__(256) void k_stage3(const u16* __restrict__ Q16g,
                                                const float* __restrict__ SSg,
                                                const float* __restrict__ rc,
                                                const float* __restrict__ rs,
                                                u16* __restrict__ RO) {
  const int tid = threadIdx.x, lane = tid & 63, wave = tid >> 6;
  const int l16 = lane & 15, q4 = lane >> 4, q8 = q4 * 8;
  const int bh = blockIdx.x >> 5, ck = blockIdx.x & 31;
  const int b = bh >> 4, h = bh & 15;
  const int tg0 = ck * 128;

  __shared__ u16 Qs[128 * 88];      // [t][d]; reused as RW [t][s]
  __shared__ u16 ss_sd[64 * 88];    // SS[s][d]
  __shared__ u16 ss_ds[64 * 88];    // SS^T[d][s]
  u16* RWs = Qs;

  const float* ssp = SSg + (size_t)bh * 4096;
  for (int i = tid; i < 4096; i += 256) {
    u16 u = f2bf(ssp[i]);
    int s = i >> 6, d = i & 63;
    ss_sd[s * 88 + d] = u;
    ss_ds[d * 88 + s] = u;
  }
  const u16* qsrc = Q16g + ((size_t)bh * TT + tg0) * 64;
  for (int idx = tid; idx < 1024; idx += 256) {
    int t = idx >> 3, p = idx & 7;
    us8v qv = *(const us8v*)(qsrc + (size_t)t * 64 + p * 8);
    int fi = (tg0 + t) * 32 + ((p * 8) & 31);
    us8v qr = rope8(qv, rc + fi, rs + fi);
    *(us8v*)&Qs[t * 88 + p * 8] = qr;
  }
  __syncthreads();

  const int w32 = wave * 32;
  // MFMA3: RL[t][s] = Q . SS^T  (wave owns 32 t-rows)
  f32x4 a3[2][4];
#pragma unroll
  for (int i = 0; i < 2; ++i)
#pragma unroll
    for (int j = 0; j < 4; ++j) a3[i][j] = (f32x4){0.f, 0.f, 0.f, 0.f};
#pragma unroll
  for (int ksx = 0; ksx < 2; ++ksx) {
    s16x8 afr[2];
#pragma unroll
    for (int im = 0; im < 2; ++im)
      afr[im] = *(const s16x8*)&Qs[(w32 + im * 16 + l16) * 88 + ksx * 32 + q8];
#pragma unroll
    for (int in = 0; in < 4; ++in) {
      s16x8 bfr = *(const s16x8*)&ss_sd[(in * 16 + l16) * 88 + ksx * 32 + q8];
#pragma unroll
      for (int im = 0; im < 2; ++im) a3[im][in] = MFMA16(afr[im], bfr, a3[im][in]);
    }
  }
  __syncthreads();

  // softmax over s, write RW[t][s] bf16
#pragma unroll
  for (int im = 0; im < 2; ++im)
#pragma unroll
    for (int reg = 0; reg < 4; ++reg) {
      float v0 = a3[im][0][reg] * 0.125f, v1 = a3[im][1][reg] * 0.125f;
      float v2 = a3[im][2][reg] * 0.125f, v3 = a3[im][3][reg] * 0.125f;
      float mx = fmaxf(fmaxf(v0, v1), fmaxf(v2, v3));
#pragma unroll
      for (int m = 1; m < 16; m <<= 1) mx = fmaxf(mx, __shfl_xor(mx, m));
      float e0 = __expf(v0 - mx), e1 = __expf(v1 - mx);
      float e2 = __expf(v2 - mx), e3 = __expf(v3 - mx);
      float sm = e0 + e1 + e2 + e3;
#pragma unroll
      for (int m = 1; m < 16; m <<= 1) sm += __shfl_xor(sm, m);
      float inv = 1.0f / sm;
      int tl = w32 + im * 16 + q4 * 4 + reg;
      RWs[tl * 88 + l16]      = f2bf(e0 * inv);
      RWs[tl * 88 + 16 + l16] = f2bf(e1 * inv);
      RWs[tl * 88 + 32 + l16] = f2bf(e2 * inv);
      RWs[tl * 88 + 48 + l16] = f2bf(e3 * inv);
    }
  __syncthreads();

  // MFMA4: RO[t][d] = RW . SS
  f32x4 a4[2][4];
#pragma unroll
  for (int i = 0; i < 2; ++i)
#pragma unroll
    for (int j = 0; j < 4; ++j) a4[i][j] = (f32x4){0.f, 0.f, 0.f, 0.f};
#pragma unroll
  for (int ksx = 0; ksx < 2; ++ksx) {
    s16x8 afr[2];
#pragma unroll
    for (int im = 0; im < 2; ++im)
      afr[im] = *(const s16x8*)&RWs[(w32 + im * 16 + l16) * 88 + ksx * 32 + q8];
#pragma unroll
    for (int in = 0; in < 4; ++in) {
      s16x8 bfr = *(const s16x8*)&ss_ds[(in * 16 + l16) * 88 + ksx * 32 + q8];
#pragma unroll
      for (int im = 0; im < 2; ++im) a4[im][in] = MFMA16(afr[im], bfr, a4[im][in]);
    }
  }

  // epilogue: RO bf16 [m][e] with m=b*T+t, e=h*64+d
#pragma unroll
  for (int im = 0; im < 2; ++im)
#pragma unroll
    for (int in = 0; in < 4; ++in)
#pragma unroll
      for (int reg = 0; reg < 4; ++reg) {
        int t = tg0 + w32 + im * 16 + q4 * 4 + reg;
        int d = in * 16 + l16;
        RO[((size_t)b * TT + t) * 1024 + h * 64 + d] = f2bf(a4[im][in][reg]);
      }
}

// ---------------- launch ----------------
extern "C" void kernel_launch(void* const* d_in, const int* in_sizes, int n_in,
                              void* d_out, int out_size, void* d_ws, size_t ws_size,
                              hipStream_t stream) {
  const float* x  = (const float*)d_in[0];
  const float* Wq = (const float*)d_in[1];
  const float* Wk = (const float*)d_in[2];
  const float* Wv = (const float*)d_in[3];
  const float* Wo = (const float*)d_in[4];
  const float* SK = (const float*)d_in[5];
  float* out = (float*)d_out;

  // workspace carve (needs ~145 MB)
  char* w = (char*)d_ws;
  u16* x16 = (u16*)w;   w += (size_t)MM * EE * 2;          // 33.5 MB
  u16* W16 = (u16*)w;   w += (size_t)3 * EE * EE * 2;      // 6.3 MB
  u16* Wo16 = (u16*)w;  w += (size_t)EE * EE * 2;          // 2.1 MB
  u16* Q16 = (u16*)w;   w += (size_t)BB * HH * TT * DD * 2; // 33.5 MB
  u16* K16 = (u16*)w;   w += (size_t)BB * HH * TT * DD * 2;
  u16* V16 = (u16*)w;   w += (size_t)BB * HH * TT * DD * 2;
  float* SSb = (float*)w; w += (size_t)BB * HH * SSLOTS * DD * 4; // 1 MB
  float* rc = (float*)w;  w += (size_t)TT * 32 * 4;
  float* rs = (float*)w;  w += (size_t)TT * 32 * 4;
  u16* RO16 = x16;  // x16 dead after QKV GEMM

  if ((size_t)(w - (char*)d_ws) > ws_size) return;  // ws too small -> loud failure

  k_prep<<<16384 + 4096 + 512, 256, 0, stream>>>(x, Wq, Wk, Wv, Wo, x16, W16, Wo16, rc, rs);

  k_gemm_qkv<<<768, 512, 0, stream>>>(x16, W16, Q16, K16, V16);

  hipMemsetAsync(SSb, 0, (size_t)BB * HH * SSLOTS * DD * 4, stream);
  k_stage2<<<512, 256, 0, stream>>>(K16, V16, SK, rc, rs, SSb);
  k_stage3<<<2048, 256, 0, stream>>>(Q16, SSb, rc, rs, RO16);

  k_gemm_out<<<256, 512, 0, stream>>>(RO16, Wo16, out);
}